// Round 10
// baseline (173.097 us; speedup 1.0000x reference)
//
#include <hip/hip_runtime.h>

#define T_N 1024
#define B_N 512
#define HID 20
#define TB3 (T_N * B_N * 3)   // 1572864
#define MEPAD 1152            // me + 128 zero-pad (kl[d<=0] = 0); serial reads to 1087

typedef float f4v __attribute__((ext_vector_type(4), aligned(4)));

__device__ __forceinline__ float bcast_lane(float v, int l) {
    return __int_as_float(__builtin_amdgcn_readlane(__float_as_int(v), l));
}

// ---------------- Kernel 1: memory MLP, LDS-staged weights (r6 proven) ----------------
__global__ __launch_bounds__(64) void me_mlp_kernel(
    const float* __restrict__ t,
    const float* __restrict__ w1, const float* __restrict__ b1,
    const float* __restrict__ w2, const float* __restrict__ b2,
    const float* __restrict__ w3, const float* __restrict__ b3,
    const float* __restrict__ w4, const float* __restrict__ b4,
    float* __restrict__ me)
{
    __shared__ float sw2[HID * HID], sw3[HID * HID];
    __shared__ float sw1[HID], sb1[HID], sb2[HID], sb3[HID], sw4[HID];
    __shared__ float sb4;
    const int tx = threadIdx.x;

    for (int i = tx; i < HID * HID; i += 64) { sw2[i] = w2[i]; sw3[i] = w3[i]; }
    for (int i = tx; i < HID; i += 64) {
        sw1[i] = w1[i]; sb1[i] = b1[i]; sb2[i] = b2[i];
        sb3[i] = b3[i]; sw4[i] = w4[i];
    }
    if (tx == 0) sb4 = b4[0];
    __syncthreads();

    const int r = blockIdx.x * 64 + tx;
    if (r >= MEPAD) return;
    if (r >= T_N) { me[r] = 0.0f; return; }

    const float x = t[r];
    float h1[HID], h2[HID], h3[HID];
    #pragma unroll
    for (int k = 0; k < HID; ++k) h1[k] = tanhf(fmaf(x, sw1[k], sb1[k]));
    for (int j = 0; j < HID; ++j) {
        float s = sb2[j];
        #pragma unroll
        for (int k = 0; k < HID; ++k) s = fmaf(h1[k], sw2[k * HID + j], s);
        h2[j] = tanhf(s);
    }
    for (int j = 0; j < HID; ++j) {
        float s = sb3[j];
        #pragma unroll
        for (int k = 0; k < HID; ++k) s = fmaf(h2[k], sw3[k * HID + j], s);
        h3[j] = tanhf(s);
    }
    float o = sb4;
    #pragma unroll
    for (int k = 0; k < HID; ++k) o = fmaf(h3[k], sw4[k], o);
    me[r] = 1.0f / (1.0f + expf(-o));
}

// ---------------- Kernel 2: ZERO-SYNC — one wave per body does everything ----------------
// integro_j = dt * sum_{d>=1} kl[d]*I[j-d], kl[d] = me[T-d] (pad: kl[d<=0]=0).
// Per chunk p (64 steps): serial recurrence carries W (this chunk, lane=c) and
// W2 (next chunk) in-register; after the chunk, the same wave accumulates
// Hmain(p+1) over chunks 0..p-1 and stores chunk p's output rows. Two
// independent waves per block (2 bodies); no barriers anywhere.
__global__ __launch_bounds__(128) void ode_kernel(
    const float* __restrict__ t,
    const float* __restrict__ y,
    const float* __restrict__ me,
    const float* __restrict__ betap,
    const float* __restrict__ gammap,
    float* __restrict__ out)
{
    const int w    = threadIdx.x >> 6;        // wave 0..1
    const int lane = threadIdx.x & 63;
    const int b    = blockIdx.x * 2 + w;      // body

    __shared__ float IhA[2][T_N];
    float* Ih = IhA[w];                       // private to this wave

    const float dt  = t[0] - t[1];            // 1/1024, exact
    const float rdt = 1.0f / dt;
    const float bet = betap[0];
    const float gam = gammap[0];
    const float Af  = dt * bet;
    const float Bf  = 1.0f - dt * gam;
    const float D2  = dt * dt;
    const float kl1 = me[T_N - 1];            // kl[1]

    float S = y[3 * b + 0];
    float I = y[3 * b + 1];
    const float Rc = S + I + y[3 * b + 2];

    if (lane < 3) {
        out[3 * b + lane] = y[3 * b + lane];                        // solution row 0
        out[TB3 + (size_t)1023 * B_N * 3 + 3 * b + lane] = 0.0f;    // diff row 1023
    }

    // Serial coefficient streams are loop-invariant -> load ONCE.
    // L[c]  = kl[lane - c]      (gk  = me + T_N - lane;  pad covers c >= lane)
    // L2[c] = kl[64 + lane - c] (gk2 = gk - 64)
    const float* gk  = me + (T_N - lane);
    const float* gk2 = gk - 64;
    f4v L[16], L2[16];
    #pragma unroll
    for (int u = 0; u < 16; ++u) {
        L[u]  = *(const f4v*)(gk  + 4 * u);
        L2[u] = *(const f4v*)(gk2 + 4 * u);
    }

    float W2 = 0.0f;   // chunk p's contribution to chunk p+1's W
    float Hm = 0.0f;   // chunks 0..p-2 contribution to chunk p's W

    for (int p = 0; p < 16; ++p) {
        const int Js = p * 64;

        // ======== serial: 64 Euler steps (r6-proven recurrence) ========
        float W = W2 + Hm;
        W2 = 0.0f;
        float mS = S, mI = I;
        const float cS = S, cI = I;          // state at chunk entry (step Js-1)
        float pre = bcast_lane(W, 0);

        {   // step 0: W-init is complete history -> no kl1 fixup
            const float A0 = p ? Af : 0.0f;  // chunk-0 step-0 = initial condition
            const float B0 = p ? Bf : 1.0f;
            const float D0 = p ? D2 : 0.0f;
            const float tot = pre;
            pre = bcast_lane(W, 1);
            const float SI = S * I;
            const float tI = B0 * I;
            const float u1 = fmaf(-A0, SI, S);
            I = fmaf(A0, SI, tI);
            S = fmaf(D0, tot, u1);
            if (lane == 0) { mS = S; mI = I; }
            W  = fmaf(L[0].x,  I, W);
            W2 = fmaf(L2[0].x, I, W2);
        }

#define BSTEP(c, KV, KV2)                                                 \
        {                                                                 \
            const float tot = fmaf(kl1, I, pre);                          \
            pre = bcast_lane(W, ((c) + 1) & 63);                          \
            const float SI = S * I;                                       \
            const float tI = Bf * I;                                      \
            const float u1 = fmaf(-Af, SI, S);                            \
            I = fmaf(Af, SI, tI);                                         \
            S = fmaf(D2, tot, u1);                                        \
            if (lane == (c)) { mS = S; mI = I; }                          \
            W  = fmaf((KV),  I, W);                                       \
            W2 = fmaf((KV2), I, W2);                                      \
        }
#define BGRP(U)                                                           \
        BSTEP(4*(U)+0, L[U].x, L2[U].x)                                   \
        BSTEP(4*(U)+1, L[U].y, L2[U].y)                                   \
        BSTEP(4*(U)+2, L[U].z, L2[U].z)                                   \
        BSTEP(4*(U)+3, L[U].w, L2[U].w)

        BSTEP(1, L[0].y, L2[0].y)
        BSTEP(2, L[0].z, L2[0].z)
        BSTEP(3, L[0].w, L2[0].w)
        BGRP(1)  BGRP(2)  BGRP(3)  BGRP(4)  BGRP(5)
        BGRP(6)  BGRP(7)  BGRP(8)  BGRP(9)  BGRP(10)
        BGRP(11) BGRP(12) BGRP(13) BGRP(14) BGRP(15)
#undef BGRP
#undef BSTEP

        // publish chunk p history (same-wave consumers only; no barrier needed)
        Ih[Js + lane] = mI;

        // ======== stores: solution row j, diff row j-1 ========
        {
            const int j = Js + lane;
            float pS = __shfl_up(mS, 1);
            float pI = __shfl_up(mI, 1);
            if (lane == 0) { pS = cS; pI = cI; }
            if (j >= 1) {
                float* so = out + (size_t)j * (B_N * 3) + 3 * b;
                so[0] = mS; so[1] = mI; so[2] = Rc - mS - mI;
                const float dSo = (mS - pS) * rdt;
                const float dIo = (mI - pI) * rdt;
                float* df = out + TB3 + (size_t)(j - 1) * (B_N * 3) + 3 * b;
                df[0] = dSo; df[1] = dIo; df[2] = -(dSo + dIo);
            }
        }

        // ======== Hmain for chunk p+1: i over chunks 0..p-1 ========
        Hm = 0.0f;
        if (p < 15) {
            const int Jt = Js + 64;
            float hm0 = 0.f, hm1 = 0.f, hm2 = 0.f, hm3 = 0.f;
            #pragma unroll 1
            for (int bb = 0; bb < p; ++bb) {
                const int i0 = 64 * bb;
                const float ihv = Ih[i0 + lane];
                const float* gq = me + (T_N - Jt + i0 - lane);   // kl[Jt+lane-(i0+q)]
                f4v Lc[16];
                #pragma unroll
                for (int u = 0; u < 16; ++u) Lc[u] = *(const f4v*)(gq + 4 * u);
                #pragma unroll
                for (int g = 0; g < 8; ++g) {
                    const float r0 = bcast_lane(ihv, 8 * g + 0);
                    const float r1 = bcast_lane(ihv, 8 * g + 1);
                    const float r2 = bcast_lane(ihv, 8 * g + 2);
                    const float r3 = bcast_lane(ihv, 8 * g + 3);
                    const float r4 = bcast_lane(ihv, 8 * g + 4);
                    const float r5 = bcast_lane(ihv, 8 * g + 5);
                    const float r6 = bcast_lane(ihv, 8 * g + 6);
                    const float r7 = bcast_lane(ihv, 8 * g + 7);
                    const f4v La = Lc[2 * g], Lb = Lc[2 * g + 1];
                    hm0 = fmaf(r0, La.x, hm0);
                    hm1 = fmaf(r1, La.y, hm1);
                    hm2 = fmaf(r2, La.z, hm2);
                    hm3 = fmaf(r3, La.w, hm3);
                    hm0 = fmaf(r4, Lb.x, hm0);
                    hm1 = fmaf(r5, Lb.y, hm1);
                    hm2 = fmaf(r6, Lb.z, hm2);
                    hm3 = fmaf(r7, Lb.w, hm3);
                }
            }
            Hm = (hm0 + hm1) + (hm2 + hm3);
        }
    }
}

// ---------------- launcher ----------------
extern "C" void kernel_launch(void* const* d_in, const int* in_sizes, int n_in,
                              void* d_out, int out_size, void* d_ws, size_t ws_size,
                              hipStream_t stream)
{
    const float* t   = (const float*)d_in[0];
    const float* y   = (const float*)d_in[1];
    const float* w1  = (const float*)d_in[2];
    const float* b1  = (const float*)d_in[3];
    const float* w2  = (const float*)d_in[4];
    const float* b2  = (const float*)d_in[5];
    const float* w3  = (const float*)d_in[6];
    const float* b3  = (const float*)d_in[7];
    const float* w4  = (const float*)d_in[8];
    const float* b4  = (const float*)d_in[9];
    const float* bet = (const float*)d_in[10];
    const float* gam = (const float*)d_in[11];
    float* out = (float*)d_out;
    float* me  = (float*)d_ws;   // 1152 floats of scratch (me + zero pad)

    me_mlp_kernel<<<dim3(MEPAD / 64), dim3(64), 0, stream>>>(
        t, w1, b1, w2, b2, w3, b3, w4, b4, me);
    ode_kernel<<<dim3(B_N / 2), dim3(128), 0, stream>>>(t, y, me, bet, gam, out);
}

// Round 11
// 146.405 us; speedup vs baseline: 1.1823x; 1.1823x over previous
//
#include <hip/hip_runtime.h>

#define T_N 1024
#define B_N 512
#define HID 20
#define TB3 (T_N * B_N * 3)   // 1572864
#define MEPAD 1152            // me + 128 zero-pad (kl[d<=0] = 0); serial reads to 1151

typedef float f4v __attribute__((ext_vector_type(4), aligned(4)));
typedef float f2v __attribute__((ext_vector_type(2), aligned(8)));
typedef float f2vu __attribute__((ext_vector_type(2), aligned(4)));

__device__ __forceinline__ float bcast_lane(float v, int l) {
    return __int_as_float(__builtin_amdgcn_readlane(__float_as_int(v), l));
}

// Barrier with LDS-only drain: all inter-wave data is in LDS, so lgkmcnt(0)
// suffices; global stores are fire-and-forget (drained at kernel end).
__device__ __forceinline__ void lds_barrier() {
    asm volatile("s_waitcnt lgkmcnt(0)\n\ts_barrier" ::: "memory");
}

// ---------------- Kernel 1: memory MLP, LDS-staged weights (r6 proven) ----------------
__global__ __launch_bounds__(64) void me_mlp_kernel(
    const float* __restrict__ t,
    const float* __restrict__ w1, const float* __restrict__ b1,
    const float* __restrict__ w2, const float* __restrict__ b2,
    const float* __restrict__ w3, const float* __restrict__ b3,
    const float* __restrict__ w4, const float* __restrict__ b4,
    float* __restrict__ me)
{
    __shared__ float sw2[HID * HID], sw3[HID * HID];
    __shared__ float sw1[HID], sb1[HID], sb2[HID], sb3[HID], sw4[HID];
    __shared__ float sb4;
    const int tx = threadIdx.x;

    for (int i = tx; i < HID * HID; i += 64) { sw2[i] = w2[i]; sw3[i] = w3[i]; }
    for (int i = tx; i < HID; i += 64) {
        sw1[i] = w1[i]; sb1[i] = b1[i]; sb2[i] = b2[i];
        sb3[i] = b3[i]; sw4[i] = w4[i];
    }
    if (tx == 0) sb4 = b4[0];
    __syncthreads();

    const int r = blockIdx.x * 64 + tx;
    if (r >= MEPAD) return;
    if (r >= T_N) { me[r] = 0.0f; return; }

    const float x = t[r];
    float h1[HID], h2[HID], h3[HID];
    #pragma unroll
    for (int k = 0; k < HID; ++k) h1[k] = tanhf(fmaf(x, sw1[k], sb1[k]));
    for (int j = 0; j < HID; ++j) {
        float s = sb2[j];
        #pragma unroll
        for (int k = 0; k < HID; ++k) s = fmaf(h1[k], sw2[k * HID + j], s);
        h2[j] = tanhf(s);
    }
    for (int j = 0; j < HID; ++j) {
        float s = sb3[j];
        #pragma unroll
        for (int k = 0; k < HID; ++k) s = fmaf(h2[k], sw3[k * HID + j], s);
        h3[j] = tanhf(s);
    }
    float o = sb4;
    #pragma unroll
    for (int k = 0; k < HID; ++k) o = fmaf(h3[k], sw4[k], o);
    me[r] = 1.0f / (1.0f + expf(-o));
}

// ---------------- Kernel 2: CHUNK=128, cheap barriers, packed LDS-broadcast conv ----------------
__global__ __launch_bounds__(256, 2) void ode_kernel(
    const float* __restrict__ t,
    const float* __restrict__ y,
    const float* __restrict__ me,
    const float* __restrict__ betap,
    const float* __restrict__ gammap,
    float* __restrict__ out)
{
    const int b    = blockIdx.x;
    const int tx   = threadIdx.x;
    const int lane = tx & 63;
    const int wv   = tx >> 6;
    const int swv  = b & 3;                 // serial wave spread across SIMDs

    __shared__ float Ih[T_N + 64];          // I trajectory (+pad)
    __shared__ float Sh[T_N + 64];          // S trajectory
    __shared__ float Hs[4][128];            // per-wave H partials for next chunk

    const float dt  = t[0] - t[1];          // 1/1024, exact
    const float rdt = 1.0f / dt;
    const float bet = betap[0];
    const float gam = gammap[0];
    const float Af  = dt * bet;
    const float Bf  = 1.0f - dt * gam;
    const float D2  = dt * dt;
    const float kl1 = me[T_N - 1];          // kl[1]

    float S = y[3 * b + 0];
    float I = y[3 * b + 1];
    const float Rc = S + I + y[3 * b + 2];

    { // zero Hs (512 floats)
        ((float*)Hs)[tx]       = 0.0f;
        ((float*)Hs)[tx + 256] = 0.0f;
    }
    if (tx == 0) { Ih[0] = I; Sh[0] = S; }
    if (tx < 3) {
        out[3 * b + tx] = y[3 * b + tx];                        // solution row 0
        out[TB3 + (size_t)1023 * B_N * 3 + 3 * b + tx] = 0.0f;  // diff row 1023
    }
    lds_barrier();

    const int rank = ((wv - swv + 4) & 3) - 1;   // helpers: 0..2; serial: -1

    for (int p = 0; p < 8; ++p) {
        const int Js = p * 128;
        const int Jn = Js + 128;
        // Hmain accumulators (packed over q): lo half c=lane, hi half c=64+lane
        f2v al0 = {0.f, 0.f}, al1 = {0.f, 0.f}, al2 = {0.f, 0.f}, al3 = {0.f, 0.f};
        f2v ah0 = {0.f, 0.f}, ah1 = {0.f, 0.f}, ah2 = {0.f, 0.f}, ah3 = {0.f, 0.f};

        if (wv == swv) {
            // ======== SERIAL: 128 Euler steps (r9-proven) ========
            float W_e = 0.f, W_o = 0.f;
            #pragma unroll
            for (int w = 0; w < 4; ++w) {
                const f2v hv = *(const f2v*)(&Hs[w][2 * lane]);
                W_e += hv.x;
                W_o += hv.y;
            }
            float pre = bcast_lane(W_e, 0);
            const float A0c = p ? Af : 0.0f;
            const float B0c = p ? Bf : 1.0f;
            const float D0c = p ? D2 : 0.0f;
            float mS_e = S, mI_e = I, mS_o = S, mI_o = I;
            const float* gke = me + (T_N - 2 * lane);   // kl[2l - c] = gke[c]
            const float* gko = gke - 1;                 // kl[2l+1 - c] = gko[c]

#define SSTEP(m, AA, BB, DD, KF, KE, KO)                                  \
            {                                                             \
                const float tot = fmaf((KF), I, pre);                     \
                pre = ((m) & 1)                                           \
                    ? bcast_lane(W_e, (hb + (((m) + 1) >> 1)) & 63)       \
                    : bcast_lane(W_o, hb + ((m) >> 1));                   \
                const float SI = S * I;                                   \
                const float tI = (BB) * I;                                \
                const float u1 = fmaf(-(AA), SI, S);                      \
                I = fmaf((AA), SI, tI);                                   \
                S = fmaf((DD), tot, u1);                                  \
                const int cc = hb + ((m) >> 1);                           \
                if ((m) & 1) { if (lane == cc) { mS_o = S; mI_o = I; } }  \
                else         { if (lane == cc) { mS_e = S; mI_e = I; } }  \
                W_e = fmaf((KE), I, W_e);                                 \
                W_o = fmaf((KO), I, W_o);                                 \
            }
#define SGRP0(AA, BB, DD, KF)                                             \
            SSTEP(0, AA, BB, DD, KF, Le[0].x, Lo[0].x)                    \
            SSTEP(1, Af, Bf, D2, kl1, Le[0].y, Lo[0].y)                   \
            SSTEP(2, Af, Bf, D2, kl1, Le[0].z, Lo[0].z)                   \
            SSTEP(3, Af, Bf, D2, kl1, Le[0].w, Lo[0].w)
#define SGRP(u)                                                           \
            SSTEP(4*(u)+0, Af, Bf, D2, kl1, Le[u].x, Lo[u].x)             \
            SSTEP(4*(u)+1, Af, Bf, D2, kl1, Le[u].y, Lo[u].y)             \
            SSTEP(4*(u)+2, Af, Bf, D2, kl1, Le[u].z, Lo[u].z)             \
            SSTEP(4*(u)+3, Af, Bf, D2, kl1, Le[u].w, Lo[u].w)

            #pragma unroll 1
            for (int s4 = 0; s4 < 4; ++s4) {
                f4v Le[8], Lo[8];
                #pragma unroll
                for (int u = 0; u < 8; ++u) {
                    Le[u] = *(const f4v*)(gke + 32 * s4 + 4 * u);
                    Lo[u] = *(const f4v*)(gko + 32 * s4 + 4 * u);
                }
                const int   hb  = 16 * s4;
                const float kf0 = (s4 == 0) ? 0.0f : kl1;
                const float Am  = (s4 == 0) ? A0c : Af;
                const float Bm  = (s4 == 0) ? B0c : Bf;
                const float Dm  = (s4 == 0) ? D0c : D2;
                SGRP0(Am, Bm, Dm, kf0)
                SGRP(1) SGRP(2) SGRP(3)
                SGRP(4) SGRP(5) SGRP(6) SGRP(7)
            }
#undef SGRP
#undef SGRP0
#undef SSTEP

            Ih[Js + 2 * lane]     = mI_e;
            Ih[Js + 2 * lane + 1] = mI_o;
            Sh[Js + 2 * lane]     = mS_e;
            Sh[Js + 2 * lane + 1] = mS_o;
        } else {
            // ======== HELPERS: store chunk p-1 + Hmain(p+1) ========
            if (p >= 1) {
                const int j0 = Js - 128;
                if (rank == 0) {
                    #pragma unroll
                    for (int h = 0; h < 2; ++h) {
                        const int j = j0 + 64 * h + lane;
                        const float s1 = Sh[j], i1 = Ih[j];
                        float* so = out + (size_t)j * (B_N * 3) + 3 * b;
                        so[0] = s1; so[1] = i1; so[2] = Rc - s1 - i1;
                    }
                } else if (rank == 1) {
                    #pragma unroll
                    for (int h = 0; h < 2; ++h) {
                        const int j = j0 + 64 * h + lane;
                        if (j >= 1) {
                            const float dS = (Sh[j] - Sh[j - 1]) * rdt;
                            const float dI = (Ih[j] - Ih[j - 1]) * rdt;
                            float* df = out + TB3 + (size_t)(j - 1) * (B_N * 3) + 3 * b;
                            df[0] = dS; df[1] = dI; df[2] = -(dS + dI);
                        }
                    }
                }
            }
            if (p < 7) {
                // Hmain(p+1): i < 128p, 64-wide segments, 3-wave round-robin.
                // Packed over q: I broadcast via uniform ds_read_b64, pk_fma.
                for (int bb = rank; bb < 2 * p; bb += 3) {
                    const int i0 = 64 * bb;
                    const float* mlo = me + (T_N - Jn - lane + i0);  // c = lane
                    const float* mhi = mlo - 64;                     // c = 64+lane
                    #pragma unroll
                    for (int g = 0; g < 4; ++g) {
                        const int qb = 16 * g;
                        const f4v cl0 = *(const f4v*)(mlo + qb);
                        const f4v cl1 = *(const f4v*)(mlo + qb + 4);
                        const f4v cl2 = *(const f4v*)(mlo + qb + 8);
                        const f4v cl3 = *(const f4v*)(mlo + qb + 12);
                        const f4v ch0 = *(const f4v*)(mhi + qb);
                        const f4v ch1 = *(const f4v*)(mhi + qb + 4);
                        const f4v ch2 = *(const f4v*)(mhi + qb + 8);
                        const f4v ch3 = *(const f4v*)(mhi + qb + 12);
                        const f2v iv0 = *(const f2v*)(&Ih[i0 + qb + 0]);
                        const f2v iv1 = *(const f2v*)(&Ih[i0 + qb + 2]);
                        const f2v iv2 = *(const f2v*)(&Ih[i0 + qb + 4]);
                        const f2v iv3 = *(const f2v*)(&Ih[i0 + qb + 6]);
                        const f2v iv4 = *(const f2v*)(&Ih[i0 + qb + 8]);
                        const f2v iv5 = *(const f2v*)(&Ih[i0 + qb + 10]);
                        const f2v iv6 = *(const f2v*)(&Ih[i0 + qb + 12]);
                        const f2v iv7 = *(const f2v*)(&Ih[i0 + qb + 14]);
                        al0 = __builtin_elementwise_fma((f2v){cl0.x, cl0.y}, iv0, al0);
                        ah0 = __builtin_elementwise_fma((f2v){ch0.x, ch0.y}, iv0, ah0);
                        al1 = __builtin_elementwise_fma((f2v){cl0.z, cl0.w}, iv1, al1);
                        ah1 = __builtin_elementwise_fma((f2v){ch0.z, ch0.w}, iv1, ah1);
                        al2 = __builtin_elementwise_fma((f2v){cl1.x, cl1.y}, iv2, al2);
                        ah2 = __builtin_elementwise_fma((f2v){ch1.x, ch1.y}, iv2, ah2);
                        al3 = __builtin_elementwise_fma((f2v){cl1.z, cl1.w}, iv3, al3);
                        ah3 = __builtin_elementwise_fma((f2v){ch1.z, ch1.w}, iv3, ah3);
                        al0 = __builtin_elementwise_fma((f2v){cl2.x, cl2.y}, iv4, al0);
                        ah0 = __builtin_elementwise_fma((f2v){ch2.x, ch2.y}, iv4, ah0);
                        al1 = __builtin_elementwise_fma((f2v){cl2.z, cl2.w}, iv5, al1);
                        ah1 = __builtin_elementwise_fma((f2v){ch2.z, ch2.w}, iv5, ah1);
                        al2 = __builtin_elementwise_fma((f2v){cl3.x, cl3.y}, iv6, al2);
                        ah2 = __builtin_elementwise_fma((f2v){ch3.x, ch3.y}, iv6, ah2);
                        al3 = __builtin_elementwise_fma((f2v){cl3.z, cl3.w}, iv7, al3);
                        ah3 = __builtin_elementwise_fma((f2v){ch3.z, ch3.w}, iv7, ah3);
                    }
                }
            }
        }
        lds_barrier();   // barrier A: chunk p published; Hmain done

        if (p < 7) {
            // ======== tail: i in [Js, Js+128), 32 per wave, all 4 waves ========
            const int i0t = Js + 32 * wv;
            const float* mlo = me + (T_N - Jn - lane + i0t);
            const float* mhi = mlo - 64;
            f2v tl0 = {0.f, 0.f}, tl1 = {0.f, 0.f};
            f2v th0 = {0.f, 0.f}, th1 = {0.f, 0.f};
            #pragma unroll
            for (int g = 0; g < 2; ++g) {
                const int qb = 16 * g;
                const f4v cl0 = *(const f4v*)(mlo + qb);
                const f4v cl1 = *(const f4v*)(mlo + qb + 4);
                const f4v cl2 = *(const f4v*)(mlo + qb + 8);
                const f4v cl3 = *(const f4v*)(mlo + qb + 12);
                const f4v ch0 = *(const f4v*)(mhi + qb);
                const f4v ch1 = *(const f4v*)(mhi + qb + 4);
                const f4v ch2 = *(const f4v*)(mhi + qb + 8);
                const f4v ch3 = *(const f4v*)(mhi + qb + 12);
                const f2v iv0 = *(const f2v*)(&Ih[i0t + qb + 0]);
                const f2v iv1 = *(const f2v*)(&Ih[i0t + qb + 2]);
                const f2v iv2 = *(const f2v*)(&Ih[i0t + qb + 4]);
                const f2v iv3 = *(const f2v*)(&Ih[i0t + qb + 6]);
                const f2v iv4 = *(const f2v*)(&Ih[i0t + qb + 8]);
                const f2v iv5 = *(const f2v*)(&Ih[i0t + qb + 10]);
                const f2v iv6 = *(const f2v*)(&Ih[i0t + qb + 12]);
                const f2v iv7 = *(const f2v*)(&Ih[i0t + qb + 14]);
                tl0 = __builtin_elementwise_fma((f2v){cl0.x, cl0.y}, iv0, tl0);
                th0 = __builtin_elementwise_fma((f2v){ch0.x, ch0.y}, iv0, th0);
                tl1 = __builtin_elementwise_fma((f2v){cl0.z, cl0.w}, iv1, tl1);
                th1 = __builtin_elementwise_fma((f2v){ch0.z, ch0.w}, iv1, th1);
                tl0 = __builtin_elementwise_fma((f2v){cl1.x, cl1.y}, iv2, tl0);
                th0 = __builtin_elementwise_fma((f2v){ch1.x, ch1.y}, iv2, th0);
                tl1 = __builtin_elementwise_fma((f2v){cl1.z, cl1.w}, iv3, tl1);
                th1 = __builtin_elementwise_fma((f2v){ch1.z, ch1.w}, iv3, th1);
                tl0 = __builtin_elementwise_fma((f2v){cl2.x, cl2.y}, iv4, tl0);
                th0 = __builtin_elementwise_fma((f2v){ch2.x, ch2.y}, iv4, th0);
                tl1 = __builtin_elementwise_fma((f2v){cl2.z, cl2.w}, iv5, tl1);
                th1 = __builtin_elementwise_fma((f2v){ch2.z, ch2.w}, iv5, th1);
                tl0 = __builtin_elementwise_fma((f2v){cl3.x, cl3.y}, iv6, tl0);
                th0 = __builtin_elementwise_fma((f2v){ch3.x, ch3.y}, iv6, th0);
                tl1 = __builtin_elementwise_fma((f2v){cl3.z, cl3.w}, iv7, tl1);
                th1 = __builtin_elementwise_fma((f2v){ch3.z, ch3.w}, iv7, th1);
            }
            const f2v sl = al0 + al1 + al2 + al3 + tl0 + tl1;
            const f2v sh = ah0 + ah1 + ah2 + ah3 + th0 + th1;
            Hs[wv][lane]      = sl.x + sl.y;
            Hs[wv][64 + lane] = sh.x + sh.y;
        }
        lds_barrier();   // barrier B: Hs ready for chunk p+1
    }

    // ======== epilogue: chunk 7 rows (896..1023; diff 895..1022) ========
    if (rank == 0) {
        #pragma unroll
        for (int h = 0; h < 2; ++h) {
            const int j = 896 + 64 * h + lane;
            const float s1 = Sh[j], i1 = Ih[j];
            float* so = out + (size_t)j * (B_N * 3) + 3 * b;
            so[0] = s1; so[1] = i1; so[2] = Rc - s1 - i1;
        }
    } else if (rank == 1) {
        #pragma unroll
        for (int h = 0; h < 2; ++h) {
            const int j = 896 + 64 * h + lane;
            const float dS = (Sh[j] - Sh[j - 1]) * rdt;
            const float dI = (Ih[j] - Ih[j - 1]) * rdt;
            float* df = out + TB3 + (size_t)(j - 1) * (B_N * 3) + 3 * b;
            df[0] = dS; df[1] = dI; df[2] = -(dS + dI);
        }
    }
}

// ---------------- launcher ----------------
extern "C" void kernel_launch(void* const* d_in, const int* in_sizes, int n_in,
                              void* d_out, int out_size, void* d_ws, size_t ws_size,
                              hipStream_t stream)
{
    const float* t   = (const float*)d_in[0];
    const float* y   = (const float*)d_in[1];
    const float* w1  = (const float*)d_in[2];
    const float* b1  = (const float*)d_in[3];
    const float* w2  = (const float*)d_in[4];
    const float* b2  = (const float*)d_in[5];
    const float* w3  = (const float*)d_in[6];
    const float* b3  = (const float*)d_in[7];
    const float* w4  = (const float*)d_in[8];
    const float* b4  = (const float*)d_in[9];
    const float* bet = (const float*)d_in[10];
    const float* gam = (const float*)d_in[11];
    float* out = (float*)d_out;
    float* me  = (float*)d_ws;   // 1152 floats of scratch (me + zero pad)

    me_mlp_kernel<<<dim3(MEPAD / 64), dim3(64), 0, stream>>>(
        t, w1, b1, w2, b2, w3, b3, w4, b4, me);
    ode_kernel<<<dim3(B_N), dim3(256), 0, stream>>>(t, y, me, bet, gam, out);
}